// Round 6
// baseline (461.596 us; speedup 1.0000x reference)
//
#include <hip/hip_runtime.h>
#include <math.h>

// ---------------------------------------------------------------------------
// SelfAttention: x(2,2048,2048) f32; wq/wk/wv/wo (2048,2048) f32.
// R6: attention restructured: 64-key K stages (double-buffered LDS, barriers
//     halved), V read direct from global (L2-resident via XCD head pinning),
//     P transform through XOR-swizzled LDS (reads 2-way=free, writes 4-way
//     vs 8-way before). GEMMs (m97-plateau) and fused RoPE epilogue kept.
// ---------------------------------------------------------------------------

typedef __bf16 bf16x8 __attribute__((ext_vector_type(8)));
typedef __bf16 bf16x4 __attribute__((ext_vector_type(4)));
typedef float  f32x4  __attribute__((ext_vector_type(4)));

#define AS1 __attribute__((address_space(1)))
#define AS3 __attribute__((address_space(3)))

static __device__ __forceinline__ void async_copy16(const void* g, void* l) {
  // per-lane global src; wave-uniform LDS base, lane i lands at base+16*i
  __builtin_amdgcn_global_load_lds((AS1 void*)g, (AS3 void*)l, 16, 0, 0);
}

// ---------------------------------------------------------------------------
// fp32 -> bf16 convert, all 5 tensors in one launch. float4 per thread.
// ---------------------------------------------------------------------------
__global__ __launch_bounds__(256) void cvt_all(
    const float* __restrict__ x,  const float* __restrict__ wq,
    const float* __restrict__ wk, const float* __restrict__ wv,
    const float* __restrict__ wo,
    __bf16* __restrict__ xb,  __bf16* __restrict__ wqb,
    __bf16* __restrict__ wkb, __bf16* __restrict__ wvb,
    __bf16* __restrict__ wob) {
  int i = blockIdx.x * 256 + threadIdx.x;  // 0 .. 6291455
  const float* in; __bf16* out; int off;
  if (i < 2097152)      { in = x;  out = xb;  off = i; }
  else if (i < 3145728) { in = wq; out = wqb; off = i - 2097152; }
  else if (i < 4194304) { in = wk; out = wkb; off = i - 3145728; }
  else if (i < 5242880) { in = wv; out = wvb; off = i - 4194304; }
  else                  { in = wo; out = wob; off = i - 5242880; }
  float4 v = ((const float4*)in)[off];
  bf16x4 o;
  o[0] = (__bf16)v.x; o[1] = (__bf16)v.y; o[2] = (__bf16)v.z; o[3] = (__bf16)v.w;
  ((bf16x4*)out)[off] = o;
}

// ---------------------------------------------------------------------------
// GEMM core: acc = A(128 rows at bm) * B^T(128 rows at bn), K=2048, m97
// staging. Wave col mapping: wave covers rows wm..wm+63 and cols
// {cw..cw+31} u {cw+64..cw+95} (cw = (wave&1)*32), so (d, d+64) head pairs
// are in-wave: colmap(j) = cw + (j&1)*16 + (j>>1)*64.
// ---------------------------------------------------------------------------
static __device__ __forceinline__ void gemm_core(const __bf16* __restrict__ A,
                                                 const __bf16* __restrict__ B,
                                                 int bm, int bn, f32x4 acc[4][4]) {
  constexpr int Kd = 2048;
  __shared__ __bf16 As[128 * 32];
  __shared__ __bf16 Bs[128 * 32];
  const int tid  = threadIdx.x;
  const int lane = tid & 63;
  const int wave = tid >> 6;
  const int l15 = lane & 15, l4 = lane >> 4;
  const int wm = (wave >> 1) * 64;
  const int cw = (wave & 1) * 32;

  const __bf16* Ag = A + (size_t)(bm + (tid >> 2)) * Kd + (tid & 3) * 8;
  const __bf16* Bg = B + (size_t)(bn + (tid >> 2)) * Kd + (tid & 3) * 8;
  __bf16* Asw = As + wave * 512;
  __bf16* Bsw = Bs + wave * 512;

  for (int k0 = 0; k0 < Kd; k0 += 32) {
    async_copy16(Ag + k0, Asw);
    async_copy16(Ag + (size_t)64 * Kd + k0, Asw + 2048);
    async_copy16(Bg + k0, Bsw);
    async_copy16(Bg + (size_t)64 * Kd + k0, Bsw + 2048);
    __syncthreads();
    bf16x8 af[4], bfr[4];
#pragma unroll
    for (int i = 0; i < 4; ++i)
      af[i] = *(const bf16x8*)&As[(wm + 16 * i + l15) * 32 + 8 * l4];
#pragma unroll
    for (int j = 0; j < 4; ++j)
      bfr[j] = *(const bf16x8*)&Bs[(cw + (j & 1) * 16 + (j >> 1) * 64 + l15) * 32 + 8 * l4];
#pragma unroll
    for (int i = 0; i < 4; ++i)
#pragma unroll
      for (int j = 0; j < 4; ++j)
        acc[i][j] = __builtin_amdgcn_mfma_f32_16x16x32_bf16(af[i], bfr[j], acc[i][j], 0, 0, 0);
    __syncthreads();
  }
}

// Fused Q/K/V projection + RoPE. grid (32,16,3); z selects weight + dest.
// z<2: rope applied in-register on fp32 acc; Q also scaled by 1/sqrt(128).
// z=2: V^T store (b, n, l).
__global__ __launch_bounds__(256) void gemm_qkv(const __bf16* __restrict__ A,
                                                const __bf16* __restrict__ wqb,
                                                const __bf16* __restrict__ wkb,
                                                const __bf16* __restrict__ wvb,
                                                __bf16* __restrict__ Qb,
                                                __bf16* __restrict__ Kb,
                                                __bf16* __restrict__ Vt) {
  const int z = blockIdx.z;
  const __bf16* B = (z == 0) ? wqb : (z == 1) ? wkb : wvb;
  const int bm = blockIdx.x * 128, bn = blockIdx.y * 128;
  f32x4 acc[4][4] = {};
  gemm_core(A, B, bm, bn, acc);

  const int lane = threadIdx.x & 63;
  const int wave = threadIdx.x >> 6;
  const int l15 = lane & 15, l4 = lane >> 4;
  const int wm = (wave >> 1) * 64;
  const int cw = (wave & 1) * 32;

  if (z < 2) {
    __bf16* C = z ? Kb : Qb;
    const float scale = z ? 1.0f : 0.08838834764831845f;  // 1/sqrt(128) on Q
    float fr[2];
#pragma unroll
    for (int jp = 0; jp < 2; ++jp) {
      const int d = cw + jp * 16 + l15;  // 0..63
      fr[jp] = exp2f((float)d * -0.20762050593045f);  // 10000^(-d/64)
    }
#pragma unroll
    for (int i = 0; i < 4; ++i) {
      const int grow0 = bm + wm + 16 * i + 4 * l4;
#pragma unroll
      for (int jp = 0; jp < 2; ++jp) {
        const int gcol = bn + cw + jp * 16 + l15;
#pragma unroll
        for (int r = 0; r < 4; ++r) {
          const int pos = (grow0 + r) & 2047;
          const float th = (float)pos * fr[jp];
          const float cv = __cosf(th), sv = __sinf(th);
          const float a1 = acc[i][jp][r], a2 = acc[i][jp + 2][r];
          C[(size_t)(grow0 + r) * 2048 + gcol]      = (__bf16)((a1 * cv - a2 * sv) * scale);
          C[(size_t)(grow0 + r) * 2048 + gcol + 64] = (__bf16)((a2 * cv + a1 * sv) * scale);
        }
      }
    }
  } else {
#pragma unroll
    for (int i = 0; i < 4; ++i) {
      const int grow0 = bm + wm + 16 * i + 4 * l4;
      const int bb = grow0 >> 11, ll = grow0 & 2047;
#pragma unroll
      for (int j = 0; j < 4; ++j) {
        const int gcol = bn + cw + (j & 1) * 16 + (j >> 1) * 64 + l15;
        bf16x4 pk;
#pragma unroll
        for (int r = 0; r < 4; ++r) pk[r] = (__bf16)acc[i][j][r];
        *(bf16x4*)(Vt + ((size_t)(bb * 2048 + gcol)) * 2048 + ll) = pk;
      }
    }
  }
}

// Output projection: f32 C row-major.
__global__ __launch_bounds__(256) void gemm_out(const __bf16* __restrict__ A,
                                                const __bf16* __restrict__ B,
                                                float* __restrict__ C) {
  const int bm = blockIdx.x * 128, bn = blockIdx.y * 128;
  f32x4 acc[4][4] = {};
  gemm_core(A, B, bm, bn, acc);
  const int lane = threadIdx.x & 63;
  const int wave = threadIdx.x >> 6;
  const int l15 = lane & 15, l4 = lane >> 4;
  const int wm = (wave >> 1) * 64;
  const int cw = (wave & 1) * 32;
#pragma unroll
  for (int i = 0; i < 4; ++i) {
    const int grow0 = bm + wm + 16 * i + 4 * l4;
#pragma unroll
    for (int j = 0; j < 4; ++j) {
      const int gcol = bn + cw + (j & 1) * 16 + (j >> 1) * 64 + l15;
#pragma unroll
      for (int r = 0; r < 4; ++r)
        C[(size_t)(grow0 + r) * 2048 + gcol] = acc[i][j][r];
    }
  }
}

// ---------------------------------------------------------------------------
// Flash attention, no-max softmax. Grid 512. WG = 4 waves; wave = 32 q rows
// (2 m-tiles of 16); block = 128 q rows.
// Per 64-key stage: K staged to LDS (4 d-slabs x [64 keys][32 elems], 16KB,
// double-buffered, 4 global_load_lds per wave, ONE barrier per 64 keys);
// 32 QK MFMAs; p=exp(min(s,40)) causal-masked; P through XOR-swizzled
// wave-private LDS (16B-chunk swizzle c^(row&7): reads 2-way free, writes
// 4-way); 4 row-sum MFMAs (ones) + 32 PV MFMAs with V-frags read DIRECT
// from global V^T (L2-resident: xcd=id&7 pins 4 heads' K/V = 4MB per XCD).
// ---------------------------------------------------------------------------
__global__ __launch_bounds__(256) void attn_flash(const __bf16* __restrict__ Q,
                                                  const __bf16* __restrict__ Km,
                                                  const __bf16* __restrict__ Vt,
                                                  __bf16* __restrict__ O) {
  __shared__ __bf16 Ks[2][8192];   // [buf][st 0..3][key 0..63][32]
  __shared__ __bf16 Pl[4][2048];   // wave-private: [m][row 0..15][64] swizzled
  const int lane = threadIdx.x & 63;
  const int wave = threadIdx.x >> 6;
  const int l15 = lane & 15, l4 = lane >> 4;

  const int id = blockIdx.x;                 // 0..511
  const int xcd = id & 7, jj = id >> 3;      // jj 0..63
  const int g = jj >> 4;                     // 0..3
  const int bh = xcd + 8 * g;                // 4 heads pinned per XCD
  const int qb = ((jj & 15) + 4 * g) & 15;   // causal depth spread
  const int qbase = qb * 128;
  const int b = bh >> 4, h = bh & 15;
  const int qw0 = qbase + wave * 32;

  // K staging source: wave w covers keys w*16..w*16+15 of each 64-key stage,
  // slab st covers d = st*32..st*32+31. Lane: key += lane>>2, 16B chunk lane&3.
  const __bf16* Kg0 = Km + ((size_t)(b * 2048 + wave * 16 + (lane >> 2))) * 2048
                         + h * 128 + (lane & 3) * 8;

  // V^T direct-load base: row = d (= dt*16 + l15), col = key (8*l4 + j)
  const __bf16* Vg0 = Vt + ((size_t)(b * 2048 + h * 128 + l15)) * 2048 + 8 * l4;

  // Q fragments: 2 m-tiles x 4 d-slabs (A-operand: m=l15, k=8*l4+j)
  bf16x8 aq[2][4];
#pragma unroll
  for (int m = 0; m < 2; ++m) {
    const __bf16* Qb2 = Q + ((size_t)(b * 2048 + qw0 + 16 * m + l15)) * 2048 + h * 128 + 8 * l4;
#pragma unroll
    for (int st = 0; st < 4; ++st) aq[m][st] = *(const bf16x8*)(Qb2 + st * 32);
  }

  bf16x8 ones;
#pragma unroll
  for (int q = 0; q < 8; ++q) ones[q] = (__bf16)1.0f;

  f32x4 oa[2][8] = {};
  f32x4 os[2] = {};

  const int nkb = qb * 2 + 2;  // 64-key stages covering keys 0 .. qbase+127

  // prologue: stage tile 0 into buf 0
#pragma unroll
  for (int st = 0; st < 4; ++st)
    async_copy16(Kg0 + st * 32, &Ks[0][st * 2048 + wave * 512]);

  for (int kb = 0; kb < nkb; ++kb) {
    const int buf = kb & 1;
    __syncthreads();  // stage kb DMA complete (all waves); prev reads done
    if (kb + 1 < nkb) {
      const size_t koff = (size_t)(kb + 1) * 64 * 2048;
      const int nb = buf ^ 1;
#pragma unroll
      for (int st = 0; st < 4; ++st)
        async_copy16(Kg0 + koff + st * 32, &Ks[nb][st * 2048 + wave * 512]);
    }
    const int kpos = kb * 64;

    // QK^T: B-frag n=key (nt*16+l15), k = st*32+8*l4+j; share across m-tiles
    f32x4 s[2][4] = {};
#pragma unroll
    for (int st = 0; st < 4; ++st)
#pragma unroll
      for (int nt = 0; nt < 4; ++nt) {
        bf16x8 bk = *(const bf16x8*)&Ks[buf][st * 2048 + (nt * 16 + l15) * 32 + 8 * l4];
#pragma unroll
        for (int m = 0; m < 2; ++m)
          s[m][nt] = __builtin_amdgcn_mfma_f32_16x16x32_bf16(aq[m][st], bk, s[m][nt], 0, 0, 0);
      }

    // p = exp(min(s,40)) masked; write to XOR-swizzled wave-private P tile.
    // P[m] logical [row 16][key 64]; 16B chunk c stored at c^(row&7).
#pragma unroll
    for (int m = 0; m < 2; ++m) {
      const int qwm = qw0 + 16 * m;
      const bool diag = (kpos + 63 > qwm);  // wave-uniform
      __bf16* pw = &Pl[wave][m * 1024];
#pragma unroll
      for (int nt = 0; nt < 4; ++nt) {
        const int col = kpos + nt * 16 + l15;
        const int cin = nt * 2 + (l15 >> 3);
#pragma unroll
        for (int r = 0; r < 4; ++r) {
          float p = __expf(fminf(s[m][nt][r], 40.f));
          if (diag && col > qwm + 4 * l4 + r) p = 0.f;
          const int rw = 4 * l4 + r;
          pw[rw * 64 + ((cin ^ (rw & 7)) * 8) + (l15 & 7)] = (__bf16)p;
        }
      }
    }

    // A-frags of P: m=l15, k = key ks*32+8*l4+j  (swizzled chunk read, 2-way)
    bf16x8 ap[2][2];
#pragma unroll
    for (int m = 0; m < 2; ++m)
#pragma unroll
      for (int ks = 0; ks < 2; ++ks)
        ap[m][ks] = *(const bf16x8*)&Pl[wave][m * 1024 + l15 * 64 + ((ks * 4 + l4) ^ (l15 & 7)) * 8];

    // row sums via ones-MFMA
#pragma unroll
    for (int m = 0; m < 2; ++m)
#pragma unroll
      for (int ks = 0; ks < 2; ++ks)
        os[m] = __builtin_amdgcn_mfma_f32_16x16x32_bf16(ap[m][ks], ones, os[m], 0, 0, 0);

    // PV: V-frags direct from global (L2): B n=d (dt*16+l15), k=key
    const __bf16* Vg = Vg0 + kpos;
#pragma unroll
    for (int dt = 0; dt < 8; ++dt)
#pragma unroll
      for (int ks = 0; ks < 2; ++ks) {
        bf16x8 bv = *(const bf16x8*)(Vg + (size_t)dt * 16 * 2048 + ks * 32);
#pragma unroll
        for (int m = 0; m < 2; ++m)
          oa[m][dt] = __builtin_amdgcn_mfma_f32_16x16x32_bf16(ap[m][ks], bv, oa[m][dt], 0, 0, 0);
      }
  }

  // epilogue: O[b, l, h, d] bf16
#pragma unroll
  for (int m = 0; m < 2; ++m) {
    float inv[4];
#pragma unroll
    for (int r = 0; r < 4; ++r) inv[r] = 1.0f / os[m][r];
    __bf16* Obase = O + ((size_t)(b * 2048 + qw0 + 16 * m + 4 * l4)) * 2048 + h * 128;
#pragma unroll
    for (int dt = 0; dt < 8; ++dt)
#pragma unroll
      for (int r = 0; r < 4; ++r)
        Obase[(size_t)r * 2048 + dt * 16 + l15] = (__bf16)(oa[m][dt][r] * inv[r]);
  }
}

// ---------------------------------------------------------------------------
extern "C" void kernel_launch(void* const* d_in, const int* in_sizes, int n_in,
                              void* d_out, int out_size, void* d_ws, size_t ws_size,
                              hipStream_t stream) {
  const float* x  = (const float*)d_in[0];
  const float* wq = (const float*)d_in[1];
  const float* wk = (const float*)d_in[2];
  const float* wv = (const float*)d_in[3];
  const float* wo = (const float*)d_in[4];

  char* ws = (char*)d_ws;
  __bf16* xb  = (__bf16*)(ws + 0);          // 16 MB (reused for O after V-proj)
  __bf16* wqb = (__bf16*)(ws + 16777216);   //  8 MB
  __bf16* wkb = (__bf16*)(ws + 25165824);
  __bf16* wvb = (__bf16*)(ws + 33554432);
  __bf16* wob = (__bf16*)(ws + 41943040);
  __bf16* Qb  = (__bf16*)(ws + 50331648);   // 16 MB
  __bf16* Kb  = (__bf16*)(ws + 67108864);   // 16 MB
  __bf16* Vt  = (__bf16*)(ws + 83886080);   // 16 MB
  __bf16* Ob  = xb;                         // alias: xb dead after V-projection

  cvt_all<<<24576, 256, 0, stream>>>(x, wq, wk, wv, wo, xb, wqb, wkb, wvb, wob);

  gemm_qkv<<<dim3(32, 16, 3), 256, 0, stream>>>(xb, wqb, wkb, wvb, Qb, Kb, Vt);

  attn_flash<<<512, 256, 0, stream>>>(Qb, Kb, Vt, Ob);

  gemm_out<<<dim3(32, 16), 256, 0, stream>>>(Ob, wob, (float*)d_out);
}